// Round 1
// baseline (247.832 us; speedup 1.0000x reference)
//
#include <hip/hip_runtime.h>

// CommLayer: y[b,a,e] = tanh( dot(xb[b,a,:], H[e,:]) + dot(S[b,:]-xb[b,a,:], C[e,:])/7 )
//          = tanh( dot(xb, M[e]) + dot(S, Cn[e]) ),  M = H - C/7, Cn = C/7
// Cast as one K=128 fp16 MFMA GEMM: A_aug[m=(b,a)] = [xb | S(b)],  B_aug[e] = [M[e] | Cn[e]]
// out flat index = m*64 + e  ==  [B, 512] row-major. Memory-bound: 256 MB -> ~41 us floor.

typedef _Float16 half4v __attribute__((ext_vector_type(4)));
typedef _Float16 half8v __attribute__((ext_vector_type(8)));
typedef float    floatx4 __attribute__((ext_vector_type(4)));

#define TILE_ROWS 16          // batch rows per tile
#define M_TILE    128         // agent rows per tile (TILE_ROWS*8)
#define LDS_STRIDE 136        // halfs per aug row: 128 + 8 pad -> 272 B row stride (16B aligned, breaks pow2 banks)
#define TILES_PER_BLOCK 2

__global__ __launch_bounds__(256, 3)
void comm_kernel(const float* __restrict__ x,
                 const float* __restrict__ Hw,
                 const float* __restrict__ Cw,
                 float* __restrict__ out)
{
    __shared__ __align__(16) _Float16 aug[M_TILE * LDS_STRIDE]; // 34816 B

    const int tid  = threadIdx.x;
    const int lane = tid & 63;
    const int wave = tid >> 6;   // 0..3
    const int quad = lane >> 4;  // 0..3
    const int l16  = lane & 15;

    // ---- Stage 0: build augmented B [64 e-rows][128 k] in LDS (coalesced), once per block ----
    // k<64: M[e][k] = H[e][k] - C[e][k]/7 ; k>=64: Cn[e][k-64] = C[e][k-64]/7
    #pragma unroll
    for (int i = 0; i < 8; ++i) {
        const int fh = (i * 256 + tid) * 4;   // half-index 0..8191, 4-aligned, thread-consecutive
        const int e = fh >> 7;
        const int k = fh & 127;
        half4v hv;
        if (k < 64) {
            const float4 h = *reinterpret_cast<const float4*>(Hw + e * 64 + k);
            const float4 c = *reinterpret_cast<const float4*>(Cw + e * 64 + k);
            hv[0] = (_Float16)(h.x - c.x * (1.0f / 7.0f));
            hv[1] = (_Float16)(h.y - c.y * (1.0f / 7.0f));
            hv[2] = (_Float16)(h.z - c.z * (1.0f / 7.0f));
            hv[3] = (_Float16)(h.w - c.w * (1.0f / 7.0f));
        } else {
            const float4 c = *reinterpret_cast<const float4*>(Cw + e * 64 + (k - 64));
            hv[0] = (_Float16)(c.x * (1.0f / 7.0f));
            hv[1] = (_Float16)(c.y * (1.0f / 7.0f));
            hv[2] = (_Float16)(c.z * (1.0f / 7.0f));
            hv[3] = (_Float16)(c.w * (1.0f / 7.0f));
        }
        *reinterpret_cast<half4v*>(&aug[e * LDS_STRIDE + k]) = hv;
    }
    __syncthreads();

    // ---- Stage 1: each lane pulls its 16 persistent B fragments into VGPRs ----
    // B-operand layout (16x16x32): n = lane&15, k = quad*8 + j  (same mapping as A; B^T/[N][K] input)
    half8v bfrag[4][4]; // [kt][nt]
    #pragma unroll
    for (int kt = 0; kt < 4; ++kt)
        #pragma unroll
        for (int nt = 0; nt < 4; ++nt)
            bfrag[kt][nt] = *reinterpret_cast<const half8v*>(
                &aug[(nt * 16 + l16) * LDS_STRIDE + kt * 32 + quad * 8]);
    __syncthreads();  // everyone done reading augB before x staging overwrites it

    #pragma unroll 1
    for (int t = 0; t < TILES_PER_BLOCK; ++t) {
        const int  tile = blockIdx.x * TILES_PER_BLOCK + t;
        const long row0 = (long)tile * TILE_ROWS;
        const float* xt = x + row0 * 512;

        if (t) __syncthreads();  // prior tile's LDS reads must drain before restaging

        // ---- Stage 2: x tile -> aug[0..127][0..63] as fp16 (coalesced dwordx4 loads) ----
        #pragma unroll
        for (int i = 0; i < 8; ++i) {
            const int flat = (tid + i * 256) * 4;     // 0..8191 floats over 16 rows x 512
            const float4 v = *reinterpret_cast<const float4*>(xt + flat);
            const int r   = flat >> 9;                // batch row in tile
            const int c   = flat & 511;
            const int row = (r << 3) + (c >> 6);      // agent-row
            const int k   = c & 63;
            half4v hv;
            hv[0] = (_Float16)v.x; hv[1] = (_Float16)v.y;
            hv[2] = (_Float16)v.z; hv[3] = (_Float16)v.w;
            *reinterpret_cast<half4v*>(&aug[row * LDS_STRIDE + k]) = hv;
        }
        __syncthreads();

        // ---- Stage 3: S[r][d] = sum_a xb, fp32 accumulate, replicate into k in [64,128) ----
        {
            const int r  = tid >> 4;          // 0..15
            const int d0 = (tid & 15) << 2;   // 0..60
            float s0 = 0.f, s1 = 0.f, s2 = 0.f, s3 = 0.f;
            #pragma unroll
            for (int a = 0; a < 8; ++a) {
                const half4v p = *reinterpret_cast<const half4v*>(
                    &aug[(r * 8 + a) * LDS_STRIDE + d0]);
                s0 += (float)p[0]; s1 += (float)p[1];
                s2 += (float)p[2]; s3 += (float)p[3];
            }
            half4v sv;
            sv[0] = (_Float16)s0; sv[1] = (_Float16)s1;
            sv[2] = (_Float16)s2; sv[3] = (_Float16)s3;
            #pragma unroll
            for (int a = 0; a < 8; ++a)
                *reinterpret_cast<half4v*>(
                    &aug[(r * 8 + a) * LDS_STRIDE + 64 + d0]) = sv;
        }
        __syncthreads();

        // ---- Stage 4: MFMA. Wave handles 32 agent-rows (2 m-tiles) x 64 cols x K=128 ----
        floatx4 acc[2][4];
        #pragma unroll
        for (int mt = 0; mt < 2; ++mt)
            #pragma unroll
            for (int nt = 0; nt < 4; ++nt)
                acc[mt][nt] = floatx4{0.f, 0.f, 0.f, 0.f};

        #pragma unroll
        for (int mt = 0; mt < 2; ++mt) {
            const int mrow = wave * 32 + mt * 16 + l16;  // A: m = lane&15, k = quad*8+j
            #pragma unroll
            for (int kt = 0; kt < 4; ++kt) {
                const half8v af = *reinterpret_cast<const half8v*>(
                    &aug[mrow * LDS_STRIDE + kt * 32 + quad * 8]);
                #pragma unroll
                for (int nt = 0; nt < 4; ++nt)
                    acc[mt][nt] = __builtin_amdgcn_mfma_f32_16x16x32_f16(
                        af, bfrag[kt][nt], acc[mt][nt], 0, 0, 0);
            }
        }

        // ---- Stage 5: tanh epilogue + store. C/D: col = lane&15, row = quad*4 + reg ----
        float* o = out + (long)tile * (M_TILE * 64);
        #pragma unroll
        for (int mt = 0; mt < 2; ++mt) {
            const int mbase = wave * 32 + mt * 16 + quad * 4;
            #pragma unroll
            for (int nt = 0; nt < 4; ++nt) {
                const int e = nt * 16 + l16;
                #pragma unroll
                for (int reg = 0; reg < 4; ++reg) {
                    float y = acc[mt][nt][reg];
                    y = fminf(10.f, fmaxf(-10.f, y));
                    // tanh(y) = (e^2y - 1)/(e^2y + 1); e^2y = exp2(y * 2/ln2)
                    const float tv = __builtin_amdgcn_exp2f(y * 2.8853900817779268f);
                    const float res = (tv - 1.f) * __builtin_amdgcn_rcpf(tv + 1.f);
                    o[(mbase + reg) * 64 + e] = res;
                }
            }
        }
    }
}

extern "C" void kernel_launch(void* const* d_in, const int* in_sizes, int n_in,
                              void* d_out, int out_size, void* d_ws, size_t ws_size,
                              hipStream_t stream) {
    const float* x  = (const float*)d_in[0];
    const float* Hw = (const float*)d_in[1];
    const float* Cw = (const float*)d_in[2];
    float* out = (float*)d_out;

    const int rows   = in_sizes[0] / 512;                    // 65536
    const int blocks = rows / (TILE_ROWS * TILES_PER_BLOCK); // 2048
    comm_kernel<<<blocks, 256, 0, stream>>>(x, Hw, Cw, out);
}